// Round 10
// baseline (425.743 us; speedup 1.0000x reference)
//
#include <hip/hip_runtime.h>

#define PMAX   50000          // valid pids are 1..49999
#define NB     196            // buckets; bucket = pid >> 8  (49999>>8 = 195)
#define BPB    256            // bins (pids) per bucket
#define OVFN   (NB * BPB)     // 50176 overflow bins, indexed by pid
#define CAP    32             // LDS entries per bucket per tile
#define GCAP   16384          // global entries per bucket (mean ~12.8K, 32-sigma margin)
#define PACK_C 16777216.0     // 2^24 : bin value = count*2^24 + sum_mse (f64-exact)
#define P1_THREADS 512
#define P1_BLOCKS  512
#define T_HITS     4096       // hits per tile (8 per thread)

// ---------------------------------------------------------------------------
// ws layout (control region = first 406528 B, memset to 0 each launch):
//   [0)        ovf bins   : OVFN f64        = 401408 B   (also the fallback bins)
//   [401408)   gcount     : NB u32 (pad)    =   1024 B
//   [402432)   partials   : NB*2 f64 (pad)  =   4096 B
//   [406528)   gbuf       : NB*GCAP u64     = 25.7 MB    (bucket mode only)
// ---------------------------------------------------------------------------
#define CTRL_BYTES 406528
#define WS_NEED_BUCKETS (CTRL_BYTES + (size_t)NB * GCAP * 8)

__device__ __forceinline__ float mse6(const float* __restrict__ pred,
                                      const float* __restrict__ tp, int i) {
    // 24 B per row, 8B-aligned -> 3x float2 (float4 would be misaligned for odd i)
    const float2* p2 = reinterpret_cast<const float2*>(pred) + (size_t)i * 3;
    const float2* t2 = reinterpret_cast<const float2*>(tp)   + (size_t)i * 3;
    float2 a0 = p2[0], a1 = p2[1], a2 = p2[2];
    float2 b0 = t2[0], b1 = t2[1], b2 = t2[2];
    float d0 = a0.x - b0.x, d1 = a0.y - b0.y, d2 = a1.x - b1.x;
    float d3 = a1.y - b1.y, d4 = a2.x - b2.x, d5 = a2.y - b2.y;
    return d0*d0 + d1*d1 + d2*d2 + d3*d3 + d4*d4 + d5*d5;
}

// ---------------------------------------------------------------------------
// Phase 1 (bucket mode): tile-staged scatter of (pid, mse) into 196 buckets.
// Per-hit cost: LDS atomic only. Global atomics: ~1 per (tile, bucket).
// ---------------------------------------------------------------------------
__global__ __launch_bounds__(P1_THREADS) void
objloss_scatter(const float* __restrict__ pred,
                const float* __restrict__ tp,
                const int* __restrict__ pid,
                const int* __restrict__ recon,
                unsigned long long* __restrict__ gbuf,
                unsigned* __restrict__ gcount,
                double* __restrict__ ovf,
                int n) {
    __shared__ unsigned long long s_buf[NB * CAP];   // 50176 B
    __shared__ unsigned s_cnt[NB];
    __shared__ unsigned s_base[NB];

    const int tid  = threadIdx.x;
    const int lane = tid & 63;
    const int wid  = tid >> 6;                       // 8 waves

    int ntiles = (n + T_HITS - 1) / T_HITS;
    for (int tile = blockIdx.x; tile < ntiles; tile += gridDim.x) {
        for (int b = tid; b < NB; b += P1_THREADS) s_cnt[b] = 0u;
        __syncthreads();

        int base_i = tile * T_HITS;
        #pragma unroll
        for (int h = 0; h < T_HITS / P1_THREADS; ++h) {
            int i = base_i + h * P1_THREADS + tid;
            if (i < n) {
                int p = pid[i];
                int r = recon[i];
                if ((r > 0) & (p > 0) & (p < PMAX)) {
                    float m = mse6(pred, tp, i);     // loads only for valid lanes
                    int b = p >> 8;
                    unsigned long long e =
                        ((unsigned long long)(unsigned)p << 32) | __float_as_uint(m);
                    unsigned idx = atomicAdd(&s_cnt[b], 1u);   // LDS atomic
                    if (idx < CAP) s_buf[b * CAP + idx] = e;
                    else atomicAdd(&ovf[p], (double)m + PACK_C);  // ~never
                }
            }
        }
        __syncthreads();

        // Flush step A: parallel slot reservation (one global atomic per bucket).
        if (tid < NB) {
            unsigned c = s_cnt[tid]; if (c > CAP) c = CAP;
            s_base[tid] = c ? atomicAdd(&gcount[tid], c) : 0u;
        }
        __syncthreads();

        // Flush step B: coalesced copy, one wave per 25 buckets.
        for (int b = wid; b < NB; b += 8) {
            unsigned c = s_cnt[b]; if (c > CAP) c = CAP;
            if (c && (unsigned)lane < c) {
                unsigned long long e = s_buf[b * CAP + lane];
                unsigned slot = s_base[b] + (unsigned)lane;
                if (slot < GCAP) {
                    gbuf[(size_t)b * GCAP + slot] = e;
                } else {                                   // bucket full: ~never
                    unsigned p = (unsigned)(e >> 32);
                    atomicAdd(&ovf[p], (double)__uint_as_float((unsigned)e) + PACK_C);
                }
            }
        }
        __syncthreads();
    }
}

// ---------------------------------------------------------------------------
// Fallback phase 1 (small ws): round-9 proven path — direct f64 packed atomics
// into ovf[pid]. gcount stays 0 so the gather kernel reads only ovf.
// ---------------------------------------------------------------------------
__global__ __launch_bounds__(256) void
objloss_accum_dev(const float* __restrict__ pred,
                  const float* __restrict__ tp,
                  const int* __restrict__ pid,
                  const int* __restrict__ recon,
                  double* __restrict__ ovf,
                  int n) {
    int i = blockIdx.x * blockDim.x + threadIdx.x;
    int base = i * 2;
    if (base >= n) return;
    int lim = (base + 2 <= n) ? 2 : 1;
    for (int k = 0; k < lim; ++k) {
        int p = pid[base + k];
        int r = recon[base + k];
        if ((r > 0) & (p > 0) & (p < PMAX)) {
            float m = mse6(pred, tp, base + k);
            atomicAdd(&ovf[p], (double)m + PACK_C);
        }
    }
}

// ---------------------------------------------------------------------------
// Phase 2: one block per bucket. LDS histogram via ds f64 atomics, add ovf,
// unpack to per-pid means, block-reduce to one partial pair.
// ---------------------------------------------------------------------------
__global__ __launch_bounds__(256) void
objloss_gather(const unsigned long long* __restrict__ gbuf,
               const unsigned* __restrict__ gcount,
               const double* __restrict__ ovf,
               double* __restrict__ partials) {
    __shared__ double s_bins[BPB];
    int b = blockIdx.x;
    int t = threadIdx.x;
    s_bins[t] = 0.0;
    __syncthreads();

    unsigned c = gcount[b]; if (c > GCAP) c = GCAP;
    for (unsigned k = t; k < c; k += 256) {
        unsigned long long e = gbuf[(size_t)b * GCAP + k];
        float m = __uint_as_float((unsigned)e);
        atomicAdd(&s_bins[(unsigned)(e >> 32) & 255u], (double)m + PACK_C); // LDS
    }
    __syncthreads();

    double v = s_bins[t] + ovf[(b << 8) | t];
    double lsum = 0.0, lk = 0.0;
    double cnt = floor(v * (1.0 / PACK_C));
    if (cnt > 0.0) { lsum = (v - cnt * PACK_C) / cnt; lk = 1.0; }

    #pragma unroll
    for (int off = 32; off > 0; off >>= 1) {
        lsum += __shfl_down(lsum, off);
        lk   += __shfl_down(lk, off);
    }
    __shared__ double ss[4], sk[4];
    int w = t >> 6, lane = t & 63;
    if (lane == 0) { ss[w] = lsum; sk[w] = lk; }
    __syncthreads();
    if (t == 0) {
        double s = 0.0, k = 0.0;
        #pragma unroll
        for (int j = 0; j < 4; ++j) { s += ss[j]; k += sk[j]; }
        partials[2 * b]     = s;
        partials[2 * b + 1] = k;
    }
}

// ---------------------------------------------------------------------------
// Final: reduce NB partial pairs -> scalar.
// ---------------------------------------------------------------------------
__global__ __launch_bounds__(256) void
objloss_final(const double* __restrict__ partials, float* __restrict__ out) {
    int t = threadIdx.x;
    double ls = 0.0, lk = 0.0;
    if (t < NB) { ls = partials[2 * t]; lk = partials[2 * t + 1]; }
    #pragma unroll
    for (int off = 32; off > 0; off >>= 1) {
        ls += __shfl_down(ls, off);
        lk += __shfl_down(lk, off);
    }
    __shared__ double ss[4], sk[4];
    int w = t >> 6, lane = t & 63;
    if (lane == 0) { ss[w] = ls; sk[w] = lk; }
    __syncthreads();
    if (t == 0) {
        double s = 0.0, k = 0.0;
        #pragma unroll
        for (int j = 0; j < 4; ++j) { s += ss[j]; k += sk[j]; }
        out[0] = (k > 0.0) ? (float)(100.0 * s / k) : 0.0f;
    }
}

extern "C" void kernel_launch(void* const* d_in, const int* in_sizes, int n_in,
                              void* d_out, int out_size, void* d_ws, size_t ws_size,
                              hipStream_t stream) {
    // Inputs: W, beta, H, pred, Y, particle_id, track_params, reconstructable
    const float* pred  = (const float*)d_in[3];
    const int*   pid   = (const int*)  d_in[5];
    const float* tp    = (const float*)d_in[6];
    const int*   recon = (const int*)  d_in[7];
    int n = in_sizes[0];  // N = 5,000,000

    char* ws = (char*)d_ws;
    double*             ovf      = (double*)ws;
    unsigned*           gcount   = (unsigned*)(ws + 401408);
    double*             partials = (double*)(ws + 402432);
    unsigned long long* gbuf     = (unsigned long long*)(ws + CTRL_BYTES);

    // Zero control region (ovf bins + gcount + partials). gbuf needs no init.
    hipMemsetAsync(d_ws, 0, CTRL_BYTES, stream);

    bool buckets = (ws_size >= WS_NEED_BUCKETS);
    if (buckets) {
        objloss_scatter<<<P1_BLOCKS, P1_THREADS, 0, stream>>>(
            pred, tp, pid, recon, gbuf, gcount, ovf, n);
    } else {
        int pairs = (n + 1) / 2;
        objloss_accum_dev<<<(pairs + 255) / 256, 256, 0, stream>>>(
            pred, tp, pid, recon, ovf, n);
    }
    objloss_gather<<<NB, 256, 0, stream>>>(gbuf, gcount, ovf, partials);
    objloss_final<<<1, 256, 0, stream>>>(partials, (float*)d_out);
}

// Round 12
// 421.060 us; speedup vs baseline: 1.0111x; 1.0111x over previous
//
#include <hip/hip_runtime.h>

#define PMAX   50000          // valid pids are 1..49999
#define NB     196            // buckets; bucket = pid >> 8  (49999>>8 = 195)
#define BPB    256            // pids per bucket
#define CAP    40             // LDS entries per bucket per tile (Pois(20.9), P(>40)~1e-4)
#define GCAP   16384          // global entries per bucket (mean ~12.8K)
#define PACK_C 16777216.0     // 2^24 : bin value = count*2^24 + sum_mse (f64-exact)
#define T_HITS 8192           // hits per tile = per block
#define P1_THREADS 512        // 8 pairs per thread

// ws layout (control region = first 406528 B, memset to 0 each launch):
//   [0)        ovf bins  : 50176 f64 = 401408 B   (also the fallback bins)
//   [401408)   gcount    : NB u32 (pad to 1024)
//   [402432)   partials  : NB*2 f64 (pad to 4096)
//   [406528)   gbuf      : NB*GCAP u32 = 12.8 MB  (bucket mode only)
#define CTRL_BYTES 406528
#define WS_NEED_BUCKETS (CTRL_BYTES + (size_t)NB * GCAP * 4)

// Entry: top 24 bits of mse f32 | low 8 bits of pid. mse >= 0 so exponent/sign
// survive; truncating 8 mantissa bits = rel err 2^-16, negligible vs threshold.
__device__ __forceinline__ unsigned make_entry(float m, int p) {
    return (__float_as_uint(m) & 0xFFFFFF00u) | ((unsigned)p & 0xFFu);
}

// ---------------------------------------------------------------------------
// Phase 1: dense-read tile scatter. Loads are UNCONDITIONAL (validity gates
// only the bin insert) so the read side is pure float4/int2 streaming.
// One tile of 8192 hits per block; 611 blocks.
// ---------------------------------------------------------------------------
__global__ __launch_bounds__(P1_THREADS) void
objloss_scatter(const float* __restrict__ pred,
                const float* __restrict__ tp,
                const int* __restrict__ pid,
                const int* __restrict__ recon,
                unsigned* __restrict__ gbuf,
                unsigned* __restrict__ gcount,
                double* __restrict__ ovf,
                int n) {
    __shared__ unsigned s_buf[NB * CAP];   // 31360 B
    __shared__ unsigned s_cnt[NB];
    __shared__ unsigned s_base[NB];

    const int tid  = threadIdx.x;
    const int lane = tid & 63;
    const int wid  = tid >> 6;             // 8 waves

    for (int b = tid; b < NB; b += P1_THREADS) s_cnt[b] = 0u;
    __syncthreads();

    const long tile0 = (long)blockIdx.x * T_HITS;

    #pragma unroll
    for (int k = 0; k < T_HITS / (2 * P1_THREADS); ++k) {
        long base = tile0 + (long)(k * P1_THREADS + tid) * 2;
        if (base + 1 < n) {
            int2 pp = *reinterpret_cast<const int2*>(pid + base);
            int2 rr = *reinterpret_cast<const int2*>(recon + base);
            const float4* pa = reinterpret_cast<const float4*>(pred + base * 6);
            const float4* tb = reinterpret_cast<const float4*>(tp   + base * 6);
            float4 a0 = pa[0], a1 = pa[1], a2 = pa[2];
            float4 b0 = tb[0], b1 = tb[1], b2 = tb[2];

            float e0 = a0.x - b0.x, e1 = a0.y - b0.y, e2 = a0.z - b0.z;
            float e3 = a0.w - b0.w, e4 = a1.x - b1.x, e5 = a1.y - b1.y;
            float m0 = e0*e0 + e1*e1 + e2*e2 + e3*e3 + e4*e4 + e5*e5;

            float f0 = a1.z - b1.z, f1 = a1.w - b1.w, f2 = a2.x - b2.x;
            float f3 = a2.y - b2.y, f4 = a2.z - b2.z, f5 = a2.w - b2.w;
            float m1 = f0*f0 + f1*f1 + f2*f2 + f3*f3 + f4*f4 + f5*f5;

            if ((rr.x > 0) & (pp.x > 0) & (pp.x < PMAX)) {
                unsigned b = (unsigned)pp.x >> 8;
                unsigned idx = atomicAdd(&s_cnt[b], 1u);
                if (idx < CAP) s_buf[b * CAP + idx] = make_entry(m0, pp.x);
                else atomicAdd(&ovf[pp.x], (double)m0 + PACK_C);   // ~never
            }
            if ((rr.y > 0) & (pp.y > 0) & (pp.y < PMAX)) {
                unsigned b = (unsigned)pp.y >> 8;
                unsigned idx = atomicAdd(&s_cnt[b], 1u);
                if (idx < CAP) s_buf[b * CAP + idx] = make_entry(m1, pp.y);
                else atomicAdd(&ovf[pp.y], (double)m1 + PACK_C);
            }
        } else if (base < n) {             // odd-n tail hit
            int p = pid[base];
            int r = recon[base];
            if ((r > 0) & (p > 0) & (p < PMAX)) {
                const float2* p2 = reinterpret_cast<const float2*>(pred) + base * 3;
                const float2* t2 = reinterpret_cast<const float2*>(tp)   + base * 3;
                float2 x0 = p2[0], x1 = p2[1], x2 = p2[2];
                float2 y0 = t2[0], y1 = t2[1], y2 = t2[2];
                float d0 = x0.x - y0.x, d1 = x0.y - y0.y, d2 = x1.x - y1.x;
                float d3 = x1.y - y1.y, d4 = x2.x - y2.x, d5 = x2.y - y2.y;
                float m = d0*d0 + d1*d1 + d2*d2 + d3*d3 + d4*d4 + d5*d5;
                atomicAdd(&ovf[p], (double)m + PACK_C);
            }
        }
    }
    __syncthreads();

    // Flush A: one global atomic per non-empty bucket (parallel over 196 lanes).
    if (tid < NB) {
        unsigned c = s_cnt[tid]; if (c > CAP) c = CAP;
        s_base[tid] = c ? atomicAdd(&gcount[tid], c) : 0u;
    }
    __syncthreads();

    // Flush B: one wave per bucket stripe (CAP=40 <= 64 lanes, single pass).
    for (int b = wid; b < NB; b += 8) {
        unsigned c = s_cnt[b]; if (c > CAP) c = CAP;
        if ((unsigned)lane < c) {
            unsigned e = s_buf[b * CAP + lane];
            unsigned slot = s_base[b] + (unsigned)lane;
            if (slot < GCAP) {
                gbuf[(size_t)b * GCAP + slot] = e;
            } else {                       // bucket full: ~never
                unsigned p = ((unsigned)b << 8) | (e & 0xFFu);
                atomicAdd(&ovf[p], (double)__uint_as_float(e & 0xFFFFFF00u) + PACK_C);
            }
        }
    }
}

// ---------------------------------------------------------------------------
// Fallback phase 1 (small ws): round-9 proven path — direct packed-f64 atomics.
// ---------------------------------------------------------------------------
__global__ __launch_bounds__(256) void
objloss_accum_dev(const float* __restrict__ pred,
                  const float* __restrict__ tp,
                  const int* __restrict__ pid,
                  const int* __restrict__ recon,
                  double* __restrict__ ovf,
                  int n) {
    int i = blockIdx.x * blockDim.x + threadIdx.x;
    long base = (long)i * 2;
    if (base >= n) return;
    int lim = (base + 2 <= n) ? 2 : 1;
    for (int k = 0; k < lim; ++k) {
        int p = pid[base + k];
        int r = recon[base + k];
        if ((r > 0) & (p > 0) & (p < PMAX)) {
            const float2* p2 = reinterpret_cast<const float2*>(pred) + (base + k) * 3;
            const float2* t2 = reinterpret_cast<const float2*>(tp)   + (base + k) * 3;
            float2 x0 = p2[0], x1 = p2[1], x2 = p2[2];
            float2 y0 = t2[0], y1 = t2[1], y2 = t2[2];
            float d0 = x0.x - y0.x, d1 = x0.y - y0.y, d2 = x1.x - y1.x;
            float d3 = x1.y - y1.y, d4 = x2.x - y2.x, d5 = x2.y - y2.y;
            float m = d0*d0 + d1*d1 + d2*d2 + d3*d3 + d4*d4 + d5*d5;
            atomicAdd(&ovf[p], (double)m + PACK_C);
        }
    }
}

// ---------------------------------------------------------------------------
// Phase 2: one block per bucket. LDS f64 histogram of the bucket's entries,
// add ovf bins, unpack to means, reduce to one partial pair.
// ---------------------------------------------------------------------------
__global__ __launch_bounds__(256) void
objloss_gather(const unsigned* __restrict__ gbuf,
               const unsigned* __restrict__ gcount,
               const double* __restrict__ ovf,
               double* __restrict__ partials) {
    __shared__ double s_bins[BPB];
    int b = blockIdx.x;
    int t = threadIdx.x;
    s_bins[t] = 0.0;
    __syncthreads();

    unsigned c = gcount[b]; if (c > GCAP) c = GCAP;
    for (unsigned k = t; k < c; k += 256) {
        unsigned e = gbuf[(size_t)b * GCAP + k];
        float m = __uint_as_float(e & 0xFFFFFF00u);
        atomicAdd(&s_bins[e & 0xFFu], (double)m + PACK_C);   // LDS atomic
    }
    __syncthreads();

    double v = s_bins[t] + ovf[(b << 8) | t];
    double lsum = 0.0, lk = 0.0;
    double cnt = floor(v * (1.0 / PACK_C));
    if (cnt > 0.0) { lsum = (v - cnt * PACK_C) / cnt; lk = 1.0; }

    #pragma unroll
    for (int off = 32; off > 0; off >>= 1) {
        lsum += __shfl_down(lsum, off);
        lk   += __shfl_down(lk, off);
    }
    __shared__ double ss[4], sk[4];
    int w = t >> 6, lane = t & 63;
    if (lane == 0) { ss[w] = lsum; sk[w] = lk; }
    __syncthreads();
    if (t == 0) {
        double s = 0.0, k = 0.0;
        #pragma unroll
        for (int j = 0; j < 4; ++j) { s += ss[j]; k += sk[j]; }
        partials[2 * b]     = s;
        partials[2 * b + 1] = k;
    }
}

// ---------------------------------------------------------------------------
// Final: reduce NB partial pairs -> scalar.
// ---------------------------------------------------------------------------
__global__ __launch_bounds__(256) void
objloss_final(const double* __restrict__ partials, float* __restrict__ out) {
    int t = threadIdx.x;
    double ls = 0.0, lk = 0.0;
    if (t < NB) { ls = partials[2 * t]; lk = partials[2 * t + 1]; }
    #pragma unroll
    for (int off = 32; off > 0; off >>= 1) {
        ls += __shfl_down(ls, off);
        lk += __shfl_down(lk, off);
    }
    __shared__ double ss[4], sk[4];
    int w = t >> 6, lane = t & 63;
    if (lane == 0) { ss[w] = ls; sk[w] = lk; }
    __syncthreads();
    if (t == 0) {
        double s = 0.0, k = 0.0;
        #pragma unroll
        for (int j = 0; j < 4; ++j) { s += ss[j]; k += sk[j]; }
        out[0] = (k > 0.0) ? (float)(100.0 * s / k) : 0.0f;
    }
}

extern "C" void kernel_launch(void* const* d_in, const int* in_sizes, int n_in,
                              void* d_out, int out_size, void* d_ws, size_t ws_size,
                              hipStream_t stream) {
    // Inputs: W, beta, H, pred, Y, particle_id, track_params, reconstructable
    const float* pred  = (const float*)d_in[3];
    const int*   pid   = (const int*)  d_in[5];
    const float* tp    = (const float*)d_in[6];
    const int*   recon = (const int*)  d_in[7];
    int n = in_sizes[0];  // N = 5,000,000

    char* ws = (char*)d_ws;
    double*   ovf      = (double*)ws;
    unsigned* gcount   = (unsigned*)(ws + 401408);
    double*   partials = (double*)(ws + 402432);
    unsigned* gbuf     = (unsigned*)(ws + CTRL_BYTES);

    hipMemsetAsync(d_ws, 0, CTRL_BYTES, stream);

    bool buckets = (ws_size >= WS_NEED_BUCKETS);
    if (buckets) {
        int ntiles = (n + T_HITS - 1) / T_HITS;
        objloss_scatter<<<ntiles, P1_THREADS, 0, stream>>>(
            pred, tp, pid, recon, gbuf, gcount, ovf, n);
    } else {
        int pairs = (n + 1) / 2;
        objloss_accum_dev<<<(pairs + 255) / 256, 256, 0, stream>>>(
            pred, tp, pid, recon, ovf, n);
    }
    objloss_gather<<<NB, 256, 0, stream>>>(gbuf, gcount, ovf, partials);
    objloss_final<<<1, 256, 0, stream>>>(partials, (float*)d_out);
}